// Round 6
// baseline (376.689 us; speedup 1.0000x reference)
//
#include <hip/hip_runtime.h>
#include <hip/hip_bf16.h>
#include <stdint.h>

// Self-attention, B=4, S=2048, D=1024, fp32 in/out, bf16 MFMA internally.
// R6: XCD-aware block swizzle (id%8 selects XCD, round-robin assumption):
//     all blocks sharing an A-tile are placed on ONE XCD consecutively, so
//     tile re-reads hit that XCD's 4MB L2 instead of HBM (~200 vs ~900 cyc
//     staging latency -> shorter barrier drains, less HBM traffic).
//     proj back to BK=32 dual-B (24 KB LDS -> 4 blocks/CU residency).
//     EXP: BK=64 dual-B (48 KB); PV: BK=64 single (32 KB).

typedef float f32x4 __attribute__((ext_vector_type(4)));
typedef short s16x8 __attribute__((ext_vector_type(8)));

__device__ __forceinline__ uint16_t f2bf(float f) {
    uint32_t u = __float_as_uint(f);
    u += 0x7fffu + ((u >> 16) & 1u);   // round-to-nearest-even
    return (uint16_t)(u >> 16);
}

#define GLOAD16(gp, lp)                                                  \
    __builtin_amdgcn_global_load_lds(                                    \
        (const __attribute__((address_space(1))) uint32_t*)(gp),         \
        (__attribute__((address_space(3))) uint32_t*)(lp), 16, 0, 0)

// ---------------------------------------------------------------------------
// Swizzles (verified conflict-free in R4: SQ_LDS_BANK_CONFLICT == 0):
// BK=32: slot cs (16B units, 512/tile) -> row cs>>2, global kchunk
//        (cs&3)^((cs>>3)&3); read offset ((lane>>4)^((lr>>1)&3))*8.
// BK=64: slot cs (1024/tile) -> row cs>>3, kchunk (cs&7)^((cs>>3)&7);
//        read offset (kc^(lr&7))*8, kc = kk*4 + (lane>>4).
// C/D layout per 16x16 tile: row=(lane>>4)*4+reg, col=lane&15.
// ---------------------------------------------------------------------------

// Projections, 1024 blocks, XCD-swizzled 1D grid:
//  id<512 (QK): m=(id>>6)*8+(id&7) in [0,64), n=(id>>3)&7. id%8=m%8 ->
//               all 8 n-blocks of one x row-tile share an XCD.
//               Q=(x@Wq^T+bq)*2^-5 ; K=x@Wk^T+bk.
//  id>=512 (VT): vid=id-512; m=(vid>>3)&7, n=(vid&7)+8*(vid>>6). id%8=n%8 ->
//               xb col-tile (B operand) shared within XCD.
//               V^T = Wv@xb^T + bv(row).
__global__ __launch_bounds__(256, 3) void proj_qkv(
    const uint16_t* __restrict__ xb, const uint16_t* __restrict__ wqb,
    const uint16_t* __restrict__ wkb, const uint16_t* __restrict__ wvb,
    const float* __restrict__ bq, const float* __restrict__ bk,
    const float* __restrict__ bv,
    uint16_t* __restrict__ qb, uint16_t* __restrict__ kb,
    uint16_t* __restrict__ vtb)
{
    __shared__ __attribute__((aligned(16))) uint16_t As[128 * 32];
    __shared__ __attribute__((aligned(16))) uint16_t Bs1[128 * 32];
    __shared__ __attribute__((aligned(16))) uint16_t Bs2[128 * 32];

    const int id = blockIdx.x;
    const bool qk = id < 512;

    const int t = threadIdx.x;
    const int wave = t >> 6, lane = t & 63;
    const int wm = (wave >> 1) * 64, wn = (wave & 1) * 64;
    const int lr = lane & 15;

    long long row0, col0;
    const uint16_t *A, *B1, *B2;
    if (qk) {
        const int m = ((id >> 6) << 3) + (id & 7);
        const int n = (id >> 3) & 7;
        row0 = (long long)m * 128;
        col0 = (long long)n * 128;
        A = xb; B1 = wqb; B2 = wkb;
    } else {
        const int vid = id - 512;
        const int m = (vid >> 3) & 7;
        const int n = (vid & 7) + ((vid >> 6) << 3);
        row0 = (long long)m * 128;
        col0 = (long long)n * 128;
        A = wvb; B1 = xb; B2 = nullptr;
    }

    // BK=32 staging: 512 slots/tile, 2 per thread per tile
    const int c0 = wave * 64 + lane;
    const int c1 = c0 + 256;
    const int kc0 = ((c0 & 3) ^ ((c0 >> 3) & 3)) * 8;
    const int kc1 = ((c1 & 3) ^ ((c1 >> 3) & 3)) * 8;
    const uint16_t* gA0  = A  + (row0 + (c0 >> 2)) * 1024 + kc0;
    const uint16_t* gA1  = A  + (row0 + (c1 >> 2)) * 1024 + kc1;
    const uint16_t* gB10 = B1 + (col0 + (c0 >> 2)) * 1024 + kc0;
    const uint16_t* gB11 = B1 + (col0 + (c1 >> 2)) * 1024 + kc1;
    const uint16_t* gB20 = qk ? B2 + (col0 + (c0 >> 2)) * 1024 + kc0 : nullptr;
    const uint16_t* gB21 = qk ? B2 + (col0 + (c1 >> 2)) * 1024 + kc1 : nullptr;
    uint16_t* lA0  = As  + wave * 512;
    uint16_t* lA1  = As  + wave * 512 + 2048;
    uint16_t* lB10 = Bs1 + wave * 512;
    uint16_t* lB11 = Bs1 + wave * 512 + 2048;
    uint16_t* lB20 = Bs2 + wave * 512;
    uint16_t* lB21 = Bs2 + wave * 512 + 2048;

    const int lka = (((lane >> 4) ^ ((lr >> 1) & 3))) * 8;

    f32x4 acc1[4][4] = {};
    f32x4 acc2[4][4] = {};

    for (int k0 = 0; k0 < 1024; k0 += 32) {
        GLOAD16(gA0 + k0, lA0);
        GLOAD16(gA1 + k0, lA1);
        GLOAD16(gB10 + k0, lB10);
        GLOAD16(gB11 + k0, lB11);
        if (qk) {
            GLOAD16(gB20 + k0, lB20);
            GLOAD16(gB21 + k0, lB21);
        }
        __syncthreads();

        s16x8 a[4], b[4];
#pragma unroll
        for (int i = 0; i < 4; ++i)
            a[i] = *(const s16x8*)(As + (wm + i * 16 + lr) * 32 + lka);
#pragma unroll
        for (int j = 0; j < 4; ++j)
            b[j] = *(const s16x8*)(Bs1 + (wn + j * 16 + lr) * 32 + lka);
#pragma unroll
        for (int i = 0; i < 4; ++i)
#pragma unroll
            for (int j = 0; j < 4; ++j)
                acc1[i][j] = __builtin_amdgcn_mfma_f32_16x16x32_bf16(
                    a[i], b[j], acc1[i][j], 0, 0, 0);
        if (qk) {
#pragma unroll
            for (int j = 0; j < 4; ++j)
                b[j] = *(const s16x8*)(Bs2 + (wn + j * 16 + lr) * 32 + lka);
#pragma unroll
            for (int i = 0; i < 4; ++i)
#pragma unroll
                for (int j = 0; j < 4; ++j)
                    acc2[i][j] = __builtin_amdgcn_mfma_f32_16x16x32_bf16(
                        a[i], b[j], acc2[i][j], 0, 0, 0);
        }
        __syncthreads();
    }

    const int rbase = wm + (lane >> 4) * 4;
    const int cbase = wn + lr;
    if (qk) {
#pragma unroll
        for (int i = 0; i < 4; ++i)
#pragma unroll
            for (int rr = 0; rr < 4; ++rr) {
                const long long row = row0 + rbase + i * 16 + rr;
#pragma unroll
                for (int j = 0; j < 4; ++j) {
                    const long long col = col0 + cbase + j * 16;
                    qb[row * 1024 + col] = f2bf((acc1[i][j][rr] + bq[col]) * 0.03125f);
                    kb[row * 1024 + col] = f2bf(acc2[i][j][rr] + bk[col]);
                }
            }
    } else {
#pragma unroll
        for (int i = 0; i < 4; ++i)
#pragma unroll
            for (int rr = 0; rr < 4; ++rr) {
                const long long row = row0 + rbase + i * 16 + rr;
                const float bb = bv[row];
#pragma unroll
                for (int j = 0; j < 4; ++j) {
                    const long long col = col0 + cbase + j * 16;
                    vtb[row * 8192 + col] = f2bf(acc1[i][j][rr] + bb);
                }
            }
    }
}

// EXP: P = exp(Q@K^T), two adjacent 128-col K-tiles per block, BK=64.
// 512 blocks, XCD-swizzled: group g=(xblk+16z) in [0,64); id = (g%8) + 8*y
// + 64*(g>>3) -> the 8 y-blocks of one Q-tile share an XCD.
__global__ __launch_bounds__(256, 3) void gemm_exp(
    const uint16_t* __restrict__ Q, const uint16_t* __restrict__ Km,
    uint16_t* __restrict__ P, float* __restrict__ sums)
{
    __shared__ __attribute__((aligned(16))) uint16_t As[128 * 64];
    __shared__ __attribute__((aligned(16))) uint16_t Bs1[128 * 64];
    __shared__ __attribute__((aligned(16))) uint16_t Bs2[128 * 64];

    const int id = blockIdx.x;
    const int g = (id & 7) + ((id >> 6) << 3);
    const int y = (id >> 3) & 7;
    const int xblk = g & 15, z = g >> 4;

    const uint16_t* Ab = Q  + (long long)z * 2048 * 1024;
    const uint16_t* Bb = Km + (long long)z * 2048 * 1024;
    uint16_t* Cb = P + (long long)z * 2048 * 2048;
    float* ax = sums + (long long)z * 2048;

    const int t = threadIdx.x;
    const int wave = t >> 6, lane = t & 63;
    const int wm = (wave >> 1) * 64, wn = (wave & 1) * 64;
    const int lr = lane & 15;
    const int lr7 = lr & 7;
    const long long row0  = (long long)xblk * 128;
    const long long col0a = (long long)y * 256;
    const long long col0b = col0a + 128;

    const uint16_t* gA[4]; const uint16_t* gB1[4]; const uint16_t* gB2[4];
    uint16_t* lA[4]; uint16_t* lB1[4]; uint16_t* lB2[4];
#pragma unroll
    for (int p = 0; p < 4; ++p) {
        const int cs = p * 256 + wave * 64 + lane;
        const int rr = cs >> 3;
        const int kc = ((cs & 7) ^ (rr & 7)) * 8;
        gA[p]  = Ab + (row0  + rr) * 1024 + kc;
        gB1[p] = Bb + (col0a + rr) * 1024 + kc;
        gB2[p] = Bb + (col0b + rr) * 1024 + kc;
        lA[p]  = As  + (p * 256 + wave * 64) * 8;
        lB1[p] = Bs1 + (p * 256 + wave * 64) * 8;
        lB2[p] = Bs2 + (p * 256 + wave * 64) * 8;
    }

    f32x4 acc1[4][4] = {};
    f32x4 acc2[4][4] = {};

    for (int k0 = 0; k0 < 1024; k0 += 64) {
#pragma unroll
        for (int p = 0; p < 4; ++p) GLOAD16(gA[p] + k0, lA[p]);
#pragma unroll
        for (int p = 0; p < 4; ++p) GLOAD16(gB1[p] + k0, lB1[p]);
#pragma unroll
        for (int p = 0; p < 4; ++p) GLOAD16(gB2[p] + k0, lB2[p]);
        __syncthreads();

#pragma unroll
        for (int kk = 0; kk < 2; ++kk) {
            const int lka = ((kk * 4 + (lane >> 4)) ^ lr7) * 8;
            s16x8 a[4], b[4];
#pragma unroll
            for (int i = 0; i < 4; ++i)
                a[i] = *(const s16x8*)(As + (wm + i * 16 + lr) * 64 + lka);
#pragma unroll
            for (int j = 0; j < 4; ++j)
                b[j] = *(const s16x8*)(Bs1 + (wn + j * 16 + lr) * 64 + lka);
#pragma unroll
            for (int i = 0; i < 4; ++i)
#pragma unroll
                for (int j = 0; j < 4; ++j)
                    acc1[i][j] = __builtin_amdgcn_mfma_f32_16x16x32_bf16(
                        a[i], b[j], acc1[i][j], 0, 0, 0);
#pragma unroll
            for (int j = 0; j < 4; ++j)
                b[j] = *(const s16x8*)(Bs2 + (wn + j * 16 + lr) * 64 + lka);
#pragma unroll
            for (int i = 0; i < 4; ++i)
#pragma unroll
                for (int j = 0; j < 4; ++j)
                    acc2[i][j] = __builtin_amdgcn_mfma_f32_16x16x32_bf16(
                        a[i], b[j], acc2[i][j], 0, 0, 0);
        }
        __syncthreads();
    }

    const int rbase = wm + (lane >> 4) * 4;
    const int cbase = wn + lr;
#pragma unroll
    for (int i = 0; i < 4; ++i)
#pragma unroll
        for (int rr = 0; rr < 4; ++rr) {
            const long long row = row0 + rbase + i * 16 + rr;
            float s = 0.f;
#pragma unroll
            for (int j = 0; j < 4; ++j) {
                const long long ca = col0a + cbase + j * 16;
                const long long cb2 = col0b + cbase + j * 16;
                const float va = __expf(acc1[i][j][rr]);
                const float vb = __expf(acc2[i][j][rr]);
                Cb[row * 2048 + ca]  = f2bf(va);
                Cb[row * 2048 + cb2] = f2bf(vb);
                s += va + vb;
            }
            s += __shfl_xor(s, 1);
            s += __shfl_xor(s, 2);
            s += __shfl_xor(s, 4);
            s += __shfl_xor(s, 8);
            if (lr == 0) atomicAdd(&ax[row], s);
        }
}

// PV: out = (P@V) * rcp(sums[row]). BK=64 single-tile. 512 blocks,
// XCD-swizzled like gemm_exp (P row-tile shared within an XCD).
__global__ __launch_bounds__(256, 4) void gemm_pv(
    const uint16_t* __restrict__ P, const uint16_t* __restrict__ Vt,
    float* __restrict__ Out, const float* __restrict__ sums)
{
    __shared__ __attribute__((aligned(16))) uint16_t As[128 * 64];
    __shared__ __attribute__((aligned(16))) uint16_t Bs[128 * 64];

    const int id = blockIdx.x;
    const int g = (id & 7) + ((id >> 6) << 3);
    const int y = (id >> 3) & 7;
    const int xblk = g & 15, z = g >> 4;

    const uint16_t* Ab = P + (long long)z * 2048 * 2048;
    const uint16_t* Bb = Vt + (long long)z * 2048;   // col offset in 8192 dim
    float* Cb = Out + (long long)z * 2048 * 1024;
    const float* ax = sums + (long long)z * 2048;

    const int t = threadIdx.x;
    const int wave = t >> 6, lane = t & 63;
    const int wm = (wave >> 1) * 64, wn = (wave & 1) * 64;
    const int lr = lane & 15;
    const int lr7 = lr & 7;
    const long long row0 = (long long)xblk * 128;
    const long long col0 = (long long)y * 128;

    const uint16_t* gA[4]; const uint16_t* gB[4];
    uint16_t* lA[4]; uint16_t* lB[4];
#pragma unroll
    for (int p = 0; p < 4; ++p) {
        const int cs = p * 256 + wave * 64 + lane;
        const int rr = cs >> 3;
        const int kc = ((cs & 7) ^ (rr & 7)) * 8;
        gA[p] = Ab + (row0 + rr) * 2048 + kc;
        gB[p] = Bb + (col0 + rr) * 8192 + kc;
        lA[p] = As + (p * 256 + wave * 64) * 8;
        lB[p] = Bs + (p * 256 + wave * 64) * 8;
    }

    f32x4 acc[4][4] = {};

    for (int k0 = 0; k0 < 2048; k0 += 64) {
#pragma unroll
        for (int p = 0; p < 4; ++p) GLOAD16(gA[p] + k0, lA[p]);
#pragma unroll
        for (int p = 0; p < 4; ++p) GLOAD16(gB[p] + k0, lB[p]);
        __syncthreads();

#pragma unroll
        for (int kk = 0; kk < 2; ++kk) {
            const int lka = ((kk * 4 + (lane >> 4)) ^ lr7) * 8;
            s16x8 a[4], b[4];
#pragma unroll
            for (int i = 0; i < 4; ++i)
                a[i] = *(const s16x8*)(As + (wm + i * 16 + lr) * 64 + lka);
#pragma unroll
            for (int j = 0; j < 4; ++j)
                b[j] = *(const s16x8*)(Bs + (wn + j * 16 + lr) * 64 + lka);
#pragma unroll
            for (int i = 0; i < 4; ++i)
#pragma unroll
                for (int j = 0; j < 4; ++j)
                    acc[i][j] = __builtin_amdgcn_mfma_f32_16x16x32_bf16(
                        a[i], b[j], acc[i][j], 0, 0, 0);
        }
        __syncthreads();
    }

    const int rbase = wm + (lane >> 4) * 4;
    const int cbase = wn + lr;
#pragma unroll
    for (int i = 0; i < 4; ++i)
#pragma unroll
        for (int rr = 0; rr < 4; ++rr) {
            const long long row = row0 + rbase + i * 16 + rr;
            const float linv = __builtin_amdgcn_rcpf(ax[row]);
#pragma unroll
            for (int j = 0; j < 4; ++j) {
                const long long col = col0 + cbase + j * 16;
                Cb[row * 1024 + col] = acc[i][j][rr] * linv;
            }
        }
}

// One dispatch: cast x (blocks 0..8191), Wq/Wk/Wv (8192..11263), zero sums.
__global__ void cast_all(const float* __restrict__ x, const float* __restrict__ Wq,
                         const float* __restrict__ Wk, const float* __restrict__ Wv,
                         uint16_t* __restrict__ xb, uint16_t* __restrict__ wqb,
                         uint16_t* __restrict__ wkb, uint16_t* __restrict__ wvb,
                         float* __restrict__ sums) {
    const int b = blockIdx.x;
    const float* in;
    uint16_t* out;
    int i;
    if (b < 8192)       { in = x;  out = xb;  i = b * 256 + threadIdx.x; }
    else if (b < 9216)  { in = Wq; out = wqb; i = (b - 8192) * 256 + threadIdx.x; }
    else if (b < 10240) { in = Wk; out = wkb; i = (b - 9216) * 256 + threadIdx.x; }
    else if (b < 11264) { in = Wv; out = wvb; i = (b - 10240) * 256 + threadIdx.x; }
    else {
        int j = (b - 11264) * 256 + threadIdx.x;   // 8 blocks x 256 x float4 = 8192
        ((float4*)sums)[j] = make_float4(0.f, 0.f, 0.f, 0.f);
        return;
    }
    float4 v = ((const float4*)in)[i];
    ushort4 o = make_ushort4(f2bf(v.x), f2bf(v.y), f2bf(v.z), f2bf(v.w));
    ((ushort4*)out)[i] = o;
}

extern "C" void kernel_launch(void* const* d_in, const int* in_sizes, int n_in,
                              void* d_out, int out_size, void* d_ws, size_t ws_size,
                              hipStream_t stream) {
    const float* x  = (const float*)d_in[0];
    const float* Wq = (const float*)d_in[1];
    const float* bq = (const float*)d_in[2];
    const float* Wk = (const float*)d_in[3];
    const float* bk = (const float*)d_in[4];
    const float* Wv = (const float*)d_in[5];
    const float* bv = (const float*)d_in[6];

    // workspace carve (~102 MiB)
    uint8_t* w = (uint8_t*)d_ws;
    uint16_t* xb  = (uint16_t*)w; w += (size_t)8192 * 1024 * 2;
    uint16_t* wqb = (uint16_t*)w; w += (size_t)1024 * 1024 * 2;
    uint16_t* wkb = (uint16_t*)w; w += (size_t)1024 * 1024 * 2;
    uint16_t* wvb = (uint16_t*)w; w += (size_t)1024 * 1024 * 2;
    uint16_t* qb  = (uint16_t*)w; w += (size_t)8192 * 1024 * 2;
    uint16_t* kb  = (uint16_t*)w; w += (size_t)8192 * 1024 * 2;
    uint16_t* vtb = (uint16_t*)w; w += (size_t)8192 * 1024 * 2;   // [1024][8192]
    uint16_t* pb  = (uint16_t*)w; w += (size_t)4 * 2048 * 2048 * 2;
    float*    sums = (float*)w;  w += (size_t)8192 * 4;

    // casts + zero the exp-sum accumulator (1 dispatch)
    cast_all<<<dim3(11272), dim3(256), 0, stream>>>(x, Wq, Wk, Wv,
                                                    xb, wqb, wkb, wvb, sums);
    // Q (pre-scaled 2^-5) & K fused, V^T single (1024 blocks, XCD-swizzled)
    proj_qkv<<<dim3(1024), 256, 0, stream>>>(xb, wqb, wkb, wvb, bq, bk, bv,
                                             qb, kb, vtb);
    // P = exp(Q @ K^T) + fused row sums (512 blocks, XCD-swizzled)
    gemm_exp<<<dim3(512), 256, 0, stream>>>(qb, kb, pb, sums);
    // out = (P @ V) * rcp(sums) (512 blocks, XCD-swizzled)
    gemm_pv<<<dim3(512), 256, 0, stream>>>(pb, vtb, (float*)d_out, sums);
}

// Round 7
// 246.677 us; speedup vs baseline: 1.5271x; 1.5271x over previous
//
#include <hip/hip_runtime.h>
#include <hip/hip_bf16.h>
#include <stdint.h>

// Self-attention, B=4, S=2048, D=1024, fp32 in/out, bf16 MFMA internally.
// R7: revert R6's XCD swizzle (regressed: write amplification + L2 pressure;
//     FETCH was never binding). Base = R5 (234.6 us). One change: gemm_pv
//     gets dual-B pairing (128q x 256e per block, two V^T tiles, 48 KB LDS)
//     -> P A-tile re-reads halve (8x->4x), 64 MFMA per barrier.

typedef float f32x4 __attribute__((ext_vector_type(4)));
typedef short s16x8 __attribute__((ext_vector_type(8)));

__device__ __forceinline__ uint16_t f2bf(float f) {
    uint32_t u = __float_as_uint(f);
    u += 0x7fffu + ((u >> 16) & 1u);   // round-to-nearest-even
    return (uint16_t)(u >> 16);
}

#define GLOAD16(gp, lp)                                                  \
    __builtin_amdgcn_global_load_lds(                                    \
        (const __attribute__((address_space(1))) uint32_t*)(gp),         \
        (__attribute__((address_space(3))) uint32_t*)(lp), 16, 0, 0)

// ---------------------------------------------------------------------------
// BK=64 swizzle (verified conflict-free, R4/R5: SQ_LDS_BANK_CONFLICT == 0):
// slot cs (16B units; 1024/tile) holds global kchunk (cs&7)^((cs>>3)&7) of
// row cs>>3; fragment read offset (kc^(lr&7))*8, kc = kk*4 + (lane>>4).
// C/D layout per 16x16 tile: row=(lane>>4)*4+reg, col=lane&15.
// ---------------------------------------------------------------------------

// Projections, 1024 blocks:
//   id < 512:  QK block. m=id>>3 (64), n=id&7 (8). A = xb row-tile;
//              Q = (A@Wq^T + bq)*2^-5 ; K = A@Wk^T + bk.
//   id >= 512: VT block. vid=id-512; m=vid&7 (8), n=vid>>3 (64).
//              V^T tile = Wv @ xb^T + bv(row).
__global__ __launch_bounds__(256, 2) void proj_qkv(
    const uint16_t* __restrict__ xb, const uint16_t* __restrict__ wqb,
    const uint16_t* __restrict__ wkb, const uint16_t* __restrict__ wvb,
    const float* __restrict__ bq, const float* __restrict__ bk,
    const float* __restrict__ bv,
    uint16_t* __restrict__ qb, uint16_t* __restrict__ kb,
    uint16_t* __restrict__ vtb)
{
    __shared__ __attribute__((aligned(16))) uint16_t As[128 * 64];
    __shared__ __attribute__((aligned(16))) uint16_t Bs1[128 * 64];
    __shared__ __attribute__((aligned(16))) uint16_t Bs2[128 * 64];

    const int id = blockIdx.x;
    const bool qk = id < 512;

    const int t = threadIdx.x;
    const int wave = t >> 6, lane = t & 63;
    const int wm = (wave >> 1) * 64, wn = (wave & 1) * 64;
    const int lr = lane & 15;
    const int lr7 = lr & 7;

    long long row0, col0;
    const uint16_t *A, *B1, *B2;
    if (qk) {
        row0 = (long long)(id >> 3) * 128;
        col0 = (long long)(id & 7) * 128;
        A = xb; B1 = wqb; B2 = wkb;
    } else {
        const int vid = id - 512;
        row0 = (long long)(vid & 7) * 128;
        col0 = (long long)(vid >> 3) * 128;
        A = wvb; B1 = xb; B2 = nullptr;
    }

    const uint16_t* gA[4]; const uint16_t* gB1[4]; const uint16_t* gB2[4];
    uint16_t* lA[4]; uint16_t* lB1[4]; uint16_t* lB2[4];
#pragma unroll
    for (int p = 0; p < 4; ++p) {
        const int cs = p * 256 + wave * 64 + lane;
        const int rr = cs >> 3;
        const int kc = ((cs & 7) ^ (rr & 7)) * 8;
        gA[p]  = A  + (row0 + rr) * 1024 + kc;
        gB1[p] = B1 + (col0 + rr) * 1024 + kc;
        if (qk) gB2[p] = B2 + (col0 + rr) * 1024 + kc;
        lA[p]  = As  + (p * 256 + wave * 64) * 8;
        lB1[p] = Bs1 + (p * 256 + wave * 64) * 8;
        lB2[p] = Bs2 + (p * 256 + wave * 64) * 8;
    }

    f32x4 acc1[4][4] = {};
    f32x4 acc2[4][4] = {};

    for (int k0 = 0; k0 < 1024; k0 += 64) {
#pragma unroll
        for (int p = 0; p < 4; ++p) GLOAD16(gA[p] + k0, lA[p]);
#pragma unroll
        for (int p = 0; p < 4; ++p) GLOAD16(gB1[p] + k0, lB1[p]);
        if (qk) {
#pragma unroll
            for (int p = 0; p < 4; ++p) GLOAD16(gB2[p] + k0, lB2[p]);
        }
        __syncthreads();

#pragma unroll
        for (int kk = 0; kk < 2; ++kk) {
            const int lka = ((kk * 4 + (lane >> 4)) ^ lr7) * 8;
            s16x8 a[4], b[4];
#pragma unroll
            for (int i = 0; i < 4; ++i)
                a[i] = *(const s16x8*)(As + (wm + i * 16 + lr) * 64 + lka);
#pragma unroll
            for (int j = 0; j < 4; ++j)
                b[j] = *(const s16x8*)(Bs1 + (wn + j * 16 + lr) * 64 + lka);
#pragma unroll
            for (int i = 0; i < 4; ++i)
#pragma unroll
                for (int j = 0; j < 4; ++j)
                    acc1[i][j] = __builtin_amdgcn_mfma_f32_16x16x32_bf16(
                        a[i], b[j], acc1[i][j], 0, 0, 0);
            if (qk) {
#pragma unroll
                for (int j = 0; j < 4; ++j)
                    b[j] = *(const s16x8*)(Bs2 + (wn + j * 16 + lr) * 64 + lka);
#pragma unroll
                for (int i = 0; i < 4; ++i)
#pragma unroll
                    for (int j = 0; j < 4; ++j)
                        acc2[i][j] = __builtin_amdgcn_mfma_f32_16x16x32_bf16(
                            a[i], b[j], acc2[i][j], 0, 0, 0);
            }
        }
        __syncthreads();
    }

    const int rbase = wm + (lane >> 4) * 4;
    const int cbase = wn + lr;
    if (qk) {
#pragma unroll
        for (int i = 0; i < 4; ++i)
#pragma unroll
            for (int rr = 0; rr < 4; ++rr) {
                const long long row = row0 + rbase + i * 16 + rr;
#pragma unroll
                for (int j = 0; j < 4; ++j) {
                    const long long col = col0 + cbase + j * 16;
                    qb[row * 1024 + col] = f2bf((acc1[i][j][rr] + bq[col]) * 0.03125f);
                    kb[row * 1024 + col] = f2bf(acc2[i][j][rr] + bk[col]);
                }
            }
    } else {
#pragma unroll
        for (int i = 0; i < 4; ++i)
#pragma unroll
            for (int rr = 0; rr < 4; ++rr) {
                const long long row = row0 + rbase + i * 16 + rr;
                const float bb = bv[row];
#pragma unroll
                for (int j = 0; j < 4; ++j) {
                    const long long col = col0 + cbase + j * 16;
                    vtb[row * 8192 + col] = f2bf(acc1[i][j][rr] + bb);
                }
            }
    }
}

// EXP: P = exp(Q@K^T) over two adjacent 128-col K-tiles per block, BK=64.
// grid (16 m, 8 col-pairs, 4 batch). Fused row-sum atomics.
__global__ __launch_bounds__(256, 2) void gemm_exp(
    const uint16_t* __restrict__ Q, const uint16_t* __restrict__ Km,
    uint16_t* __restrict__ P, float* __restrict__ sums)
{
    __shared__ __attribute__((aligned(16))) uint16_t As[128 * 64];
    __shared__ __attribute__((aligned(16))) uint16_t Bs1[128 * 64];
    __shared__ __attribute__((aligned(16))) uint16_t Bs2[128 * 64];

    const int z = blockIdx.z;
    const uint16_t* Ab = Q  + (long long)z * 2048 * 1024;
    const uint16_t* Bb = Km + (long long)z * 2048 * 1024;
    uint16_t* Cb = P + (long long)z * 2048 * 2048;
    float* ax = sums + (long long)z * 2048;

    const int t = threadIdx.x;
    const int wave = t >> 6, lane = t & 63;
    const int wm = (wave >> 1) * 64, wn = (wave & 1) * 64;
    const int lr = lane & 15;
    const int lr7 = lr & 7;
    const long long row0  = (long long)blockIdx.x * 128;
    const long long col0a = (long long)blockIdx.y * 256;
    const long long col0b = col0a + 128;

    const uint16_t* gA[4]; const uint16_t* gB1[4]; const uint16_t* gB2[4];
    uint16_t* lA[4]; uint16_t* lB1[4]; uint16_t* lB2[4];
#pragma unroll
    for (int p = 0; p < 4; ++p) {
        const int cs = p * 256 + wave * 64 + lane;
        const int rr = cs >> 3;
        const int kc = ((cs & 7) ^ (rr & 7)) * 8;
        gA[p]  = Ab + (row0  + rr) * 1024 + kc;
        gB1[p] = Bb + (col0a + rr) * 1024 + kc;
        gB2[p] = Bb + (col0b + rr) * 1024 + kc;
        lA[p]  = As  + (p * 256 + wave * 64) * 8;
        lB1[p] = Bs1 + (p * 256 + wave * 64) * 8;
        lB2[p] = Bs2 + (p * 256 + wave * 64) * 8;
    }

    f32x4 acc1[4][4] = {};
    f32x4 acc2[4][4] = {};

    for (int k0 = 0; k0 < 1024; k0 += 64) {
#pragma unroll
        for (int p = 0; p < 4; ++p) GLOAD16(gA[p] + k0, lA[p]);
#pragma unroll
        for (int p = 0; p < 4; ++p) GLOAD16(gB1[p] + k0, lB1[p]);
#pragma unroll
        for (int p = 0; p < 4; ++p) GLOAD16(gB2[p] + k0, lB2[p]);
        __syncthreads();

#pragma unroll
        for (int kk = 0; kk < 2; ++kk) {
            const int lka = ((kk * 4 + (lane >> 4)) ^ lr7) * 8;
            s16x8 a[4], b[4];
#pragma unroll
            for (int i = 0; i < 4; ++i)
                a[i] = *(const s16x8*)(As + (wm + i * 16 + lr) * 64 + lka);
#pragma unroll
            for (int j = 0; j < 4; ++j)
                b[j] = *(const s16x8*)(Bs1 + (wn + j * 16 + lr) * 64 + lka);
#pragma unroll
            for (int i = 0; i < 4; ++i)
#pragma unroll
                for (int j = 0; j < 4; ++j)
                    acc1[i][j] = __builtin_amdgcn_mfma_f32_16x16x32_bf16(
                        a[i], b[j], acc1[i][j], 0, 0, 0);
#pragma unroll
            for (int j = 0; j < 4; ++j)
                b[j] = *(const s16x8*)(Bs2 + (wn + j * 16 + lr) * 64 + lka);
#pragma unroll
            for (int i = 0; i < 4; ++i)
#pragma unroll
                for (int j = 0; j < 4; ++j)
                    acc2[i][j] = __builtin_amdgcn_mfma_f32_16x16x32_bf16(
                        a[i], b[j], acc2[i][j], 0, 0, 0);
        }
        __syncthreads();
    }

    const int rbase = wm + (lane >> 4) * 4;
    const int cbase = wn + lr;
#pragma unroll
    for (int i = 0; i < 4; ++i)
#pragma unroll
        for (int rr = 0; rr < 4; ++rr) {
            const long long row = row0 + rbase + i * 16 + rr;
            float s = 0.f;
#pragma unroll
            for (int j = 0; j < 4; ++j) {
                const long long ca = col0a + cbase + j * 16;
                const long long cb2 = col0b + cbase + j * 16;
                const float va = __expf(acc1[i][j][rr]);
                const float vb = __expf(acc2[i][j][rr]);
                Cb[row * 2048 + ca]  = f2bf(va);
                Cb[row * 2048 + cb2] = f2bf(vb);
                s += va + vb;
            }
            s += __shfl_xor(s, 1);
            s += __shfl_xor(s, 2);
            s += __shfl_xor(s, 4);
            s += __shfl_xor(s, 8);
            if (lr == 0) atomicAdd(&ax[row], s);
        }
}

// PV: out = (P@V) * rcp(sums[row]). Dual-B: two adjacent 128-e V^T tiles per
// block (128q x 256e output), BK=64, 48 KB LDS. grid (16, 4, 4) = 256 blocks.
__global__ __launch_bounds__(256, 2) void gemm_pv(
    const uint16_t* __restrict__ P, const uint16_t* __restrict__ Vt,
    float* __restrict__ Out, const float* __restrict__ sums)
{
    __shared__ __attribute__((aligned(16))) uint16_t As[128 * 64];
    __shared__ __attribute__((aligned(16))) uint16_t Bs1[128 * 64];
    __shared__ __attribute__((aligned(16))) uint16_t Bs2[128 * 64];

    const int z = blockIdx.z;
    const uint16_t* Ab = P + (long long)z * 2048 * 2048;
    const uint16_t* Bb = Vt + (long long)z * 2048;   // col offset in 8192 dim
    float* Cb = Out + (long long)z * 2048 * 1024;
    const float* ax = sums + (long long)z * 2048;

    const int t = threadIdx.x;
    const int wave = t >> 6, lane = t & 63;
    const int wm = (wave >> 1) * 64, wn = (wave & 1) * 64;
    const int lr = lane & 15;
    const int lr7 = lr & 7;
    const long long row0  = (long long)blockIdx.x * 128;
    const long long col0a = (long long)blockIdx.y * 256;
    const long long col0b = col0a + 128;

    const uint16_t* gA[4]; const uint16_t* gB1[4]; const uint16_t* gB2[4];
    uint16_t* lA[4]; uint16_t* lB1[4]; uint16_t* lB2[4];
#pragma unroll
    for (int p = 0; p < 4; ++p) {
        const int cs = p * 256 + wave * 64 + lane;
        const int rr = cs >> 3;
        const int kc = ((cs & 7) ^ (rr & 7)) * 8;
        gA[p]  = Ab + (row0  + rr) * 2048 + kc;
        gB1[p] = Bb + (col0a + rr) * 8192 + kc;
        gB2[p] = Bb + (col0b + rr) * 8192 + kc;
        lA[p]  = As  + (p * 256 + wave * 64) * 8;
        lB1[p] = Bs1 + (p * 256 + wave * 64) * 8;
        lB2[p] = Bs2 + (p * 256 + wave * 64) * 8;
    }

    f32x4 acc1[4][4] = {};
    f32x4 acc2[4][4] = {};

    for (int k0 = 0; k0 < 2048; k0 += 64) {
#pragma unroll
        for (int p = 0; p < 4; ++p) GLOAD16(gA[p] + k0, lA[p]);
#pragma unroll
        for (int p = 0; p < 4; ++p) GLOAD16(gB1[p] + k0, lB1[p]);
#pragma unroll
        for (int p = 0; p < 4; ++p) GLOAD16(gB2[p] + k0, lB2[p]);
        __syncthreads();

#pragma unroll
        for (int kk = 0; kk < 2; ++kk) {
            const int lka = ((kk * 4 + (lane >> 4)) ^ lr7) * 8;
            s16x8 a[4], b[4];
#pragma unroll
            for (int i = 0; i < 4; ++i)
                a[i] = *(const s16x8*)(As + (wm + i * 16 + lr) * 64 + lka);
#pragma unroll
            for (int j = 0; j < 4; ++j)
                b[j] = *(const s16x8*)(Bs1 + (wn + j * 16 + lr) * 64 + lka);
#pragma unroll
            for (int i = 0; i < 4; ++i)
#pragma unroll
                for (int j = 0; j < 4; ++j)
                    acc1[i][j] = __builtin_amdgcn_mfma_f32_16x16x32_bf16(
                        a[i], b[j], acc1[i][j], 0, 0, 0);
#pragma unroll
            for (int j = 0; j < 4; ++j)
                b[j] = *(const s16x8*)(Bs2 + (wn + j * 16 + lr) * 64 + lka);
#pragma unroll
            for (int i = 0; i < 4; ++i)
#pragma unroll
                for (int j = 0; j < 4; ++j)
                    acc2[i][j] = __builtin_amdgcn_mfma_f32_16x16x32_bf16(
                        a[i], b[j], acc2[i][j], 0, 0, 0);
        }
        __syncthreads();
    }

    const int rbase = wm + (lane >> 4) * 4;
    const int cbase = wn + lr;
#pragma unroll
    for (int i = 0; i < 4; ++i)
#pragma unroll
        for (int rr = 0; rr < 4; ++rr) {
            const long long row = row0 + rbase + i * 16 + rr;
            const float linv = __builtin_amdgcn_rcpf(ax[row]);
#pragma unroll
            for (int j = 0; j < 4; ++j) {
                const long long ca = col0a + cbase + j * 16;
                const long long cb2 = col0b + cbase + j * 16;
                Cb[row * 1024 + ca]  = acc1[i][j][rr] * linv;
                Cb[row * 1024 + cb2] = acc2[i][j][rr] * linv;
            }
        }
}

// One dispatch: cast x (blocks 0..8191), Wq/Wk/Wv (8192..11263), zero sums.
__global__ void cast_all(const float* __restrict__ x, const float* __restrict__ Wq,
                         const float* __restrict__ Wk, const float* __restrict__ Wv,
                         uint16_t* __restrict__ xb, uint16_t* __restrict__ wqb,
                         uint16_t* __restrict__ wkb, uint16_t* __restrict__ wvb,
                         float* __restrict__ sums) {
    const int b = blockIdx.x;
    const float* in;
    uint16_t* out;
    int i;
    if (b < 8192)       { in = x;  out = xb;  i = b * 256 + threadIdx.x; }
    else if (b < 9216)  { in = Wq; out = wqb; i = (b - 8192) * 256 + threadIdx.x; }
    else if (b < 10240) { in = Wk; out = wkb; i = (b - 9216) * 256 + threadIdx.x; }
    else if (b < 11264) { in = Wv; out = wvb; i = (b - 10240) * 256 + threadIdx.x; }
    else {
        int j = (b - 11264) * 256 + threadIdx.x;   // 8 blocks x 256 x float4 = 8192
        ((float4*)sums)[j] = make_float4(0.f, 0.f, 0.f, 0.f);
        return;
    }
    float4 v = ((const float4*)in)[i];
    ushort4 o = make_ushort4(f2bf(v.x), f2bf(v.y), f2bf(v.z), f2bf(v.w));
    ((ushort4*)out)[i] = o;
}

extern "C" void kernel_launch(void* const* d_in, const int* in_sizes, int n_in,
                              void* d_out, int out_size, void* d_ws, size_t ws_size,
                              hipStream_t stream) {
    const float* x  = (const float*)d_in[0];
    const float* Wq = (const float*)d_in[1];
    const float* bq = (const float*)d_in[2];
    const float* Wk = (const float*)d_in[3];
    const float* bk = (const float*)d_in[4];
    const float* Wv = (const float*)d_in[5];
    const float* bv = (const float*)d_in[6];

    // workspace carve (~102 MiB)
    uint8_t* w = (uint8_t*)d_ws;
    uint16_t* xb  = (uint16_t*)w; w += (size_t)8192 * 1024 * 2;
    uint16_t* wqb = (uint16_t*)w; w += (size_t)1024 * 1024 * 2;
    uint16_t* wkb = (uint16_t*)w; w += (size_t)1024 * 1024 * 2;
    uint16_t* wvb = (uint16_t*)w; w += (size_t)1024 * 1024 * 2;
    uint16_t* qb  = (uint16_t*)w; w += (size_t)8192 * 1024 * 2;
    uint16_t* kb  = (uint16_t*)w; w += (size_t)8192 * 1024 * 2;
    uint16_t* vtb = (uint16_t*)w; w += (size_t)8192 * 1024 * 2;   // [1024][8192]
    uint16_t* pb  = (uint16_t*)w; w += (size_t)4 * 2048 * 2048 * 2;
    float*    sums = (float*)w;  w += (size_t)8192 * 4;

    // casts + zero the exp-sum accumulator (1 dispatch)
    cast_all<<<dim3(11272), dim3(256), 0, stream>>>(x, Wq, Wk, Wv,
                                                    xb, wqb, wkb, wvb, sums);
    // Q (pre-scaled 2^-5) & K fused, V^T single (1024 blocks)
    proj_qkv<<<dim3(1024), 256, 0, stream>>>(xb, wqb, wkb, wvb, bq, bk, bv,
                                             qb, kb, vtb);
    // P = exp(Q @ K^T) + fused row sums, two K-col tiles per block
    gemm_exp<<<dim3(16, 8, 4), 256, 0, stream>>>(qb, kb, pb, sums);
    // out = (P @ V) * rcp(sums), two V^T e-tiles per block
    gemm_pv<<<dim3(16, 4, 4), 256, 0, stream>>>(pb, vtb, (float*)d_out, sums);
}

// Round 8
// 236.263 us; speedup vs baseline: 1.5944x; 1.0441x over previous
//
#include <hip/hip_runtime.h>
#include <hip/hip_bf16.h>
#include <stdint.h>

// Self-attention, B=4, S=2048, D=1024, fp32 in/out, bf16 MFMA internally.
// R8: base = R5 (best, 234.6 us). PV reverted to single-B 512 blocks
//     (R7 showed 2 blocks/CU co-residency > traffic cut). proj made
//     uniformly dual-B: VT blocks now pair two xb col-tiles (256 VT blocks,
//     same 12-glds/128-MFMA inner loop as QK) -> balanced packing, branch-
//     free K-loop, 2x MFMA-per-barrier on the VT half. Grid 768, 2QK+1VT
//     per id-triple.

typedef float f32x4 __attribute__((ext_vector_type(4)));
typedef short s16x8 __attribute__((ext_vector_type(8)));

__device__ __forceinline__ uint16_t f2bf(float f) {
    uint32_t u = __float_as_uint(f);
    u += 0x7fffu + ((u >> 16) & 1u);   // round-to-nearest-even
    return (uint16_t)(u >> 16);
}

#define GLOAD16(gp, lp)                                                  \
    __builtin_amdgcn_global_load_lds(                                    \
        (const __attribute__((address_space(1))) uint32_t*)(gp),         \
        (__attribute__((address_space(3))) uint32_t*)(lp), 16, 0, 0)

// ---------------------------------------------------------------------------
// BK=64 swizzle (verified conflict-free, R4-R7: SQ_LDS_BANK_CONFLICT == 0):
// slot cs (16B units; 1024/tile) holds global kchunk (cs&7)^((cs>>3)&7) of
// row cs>>3; fragment read offset (kc^(lr&7))*8, kc = kk*4 + (lane>>4).
// C/D layout per 16x16 tile: row=(lane>>4)*4+reg, col=lane&15.
// ---------------------------------------------------------------------------

// Projections, 768 blocks, uniform dual-B. id triple: r3=id%3.
//   r3<2 (QK): qkid=g3*2+r3 in [0,512). m=qkid>>3, n=qkid&7.
//              A=xb row-tile; B1=Wq, B2=Wk at col n*128.
//              Q=(A@B1^T+bq)*2^-5 ; K=A@B2^T+bk.
//   r3==2 (VT): g3 in [0,256). m=g3>>5 (8), npair=g3&31 (32).
//              A=Wv row-tile; B1=xb col npair*256, B2=+128.
//              V^T = A@xb^T + bv(row), two 128-col tiles.
__global__ __launch_bounds__(256, 2) void proj_qkv(
    const uint16_t* __restrict__ xb, const uint16_t* __restrict__ wqb,
    const uint16_t* __restrict__ wkb, const uint16_t* __restrict__ wvb,
    const float* __restrict__ bq, const float* __restrict__ bk,
    const float* __restrict__ bv,
    uint16_t* __restrict__ qb, uint16_t* __restrict__ kb,
    uint16_t* __restrict__ vtb)
{
    __shared__ __attribute__((aligned(16))) uint16_t As[128 * 64];
    __shared__ __attribute__((aligned(16))) uint16_t Bs1[128 * 64];
    __shared__ __attribute__((aligned(16))) uint16_t Bs2[128 * 64];

    const int id = blockIdx.x;
    const int g3 = id / 3;
    const int r3 = id - g3 * 3;
    const bool qk = r3 < 2;

    const int t = threadIdx.x;
    const int wave = t >> 6, lane = t & 63;
    const int wm = (wave >> 1) * 64, wn = (wave & 1) * 64;
    const int lr = lane & 15;
    const int lr7 = lr & 7;

    long long row0, col0a, col0b;
    const uint16_t *A, *B1, *B2;
    if (qk) {
        const int qkid = g3 * 2 + r3;
        row0  = (long long)(qkid >> 3) * 128;
        col0a = (long long)(qkid & 7) * 128;
        col0b = col0a;
        A = xb; B1 = wqb; B2 = wkb;
    } else {
        row0  = (long long)(g3 >> 5) * 128;
        col0a = (long long)(g3 & 31) * 256;
        col0b = col0a + 128;
        A = wvb; B1 = xb; B2 = xb;
    }

    const uint16_t* gA[4]; const uint16_t* gB1[4]; const uint16_t* gB2[4];
    uint16_t* lA[4]; uint16_t* lB1[4]; uint16_t* lB2[4];
#pragma unroll
    for (int p = 0; p < 4; ++p) {
        const int cs = p * 256 + wave * 64 + lane;
        const int rr = cs >> 3;
        const int kc = ((cs & 7) ^ (rr & 7)) * 8;
        gA[p]  = A  + (row0  + rr) * 1024 + kc;
        gB1[p] = B1 + (col0a + rr) * 1024 + kc;
        gB2[p] = B2 + (col0b + rr) * 1024 + kc;
        lA[p]  = As  + (p * 256 + wave * 64) * 8;
        lB1[p] = Bs1 + (p * 256 + wave * 64) * 8;
        lB2[p] = Bs2 + (p * 256 + wave * 64) * 8;
    }

    f32x4 acc1[4][4] = {};
    f32x4 acc2[4][4] = {};

    for (int k0 = 0; k0 < 1024; k0 += 64) {
#pragma unroll
        for (int p = 0; p < 4; ++p) GLOAD16(gA[p] + k0, lA[p]);
#pragma unroll
        for (int p = 0; p < 4; ++p) GLOAD16(gB1[p] + k0, lB1[p]);
#pragma unroll
        for (int p = 0; p < 4; ++p) GLOAD16(gB2[p] + k0, lB2[p]);
        __syncthreads();

#pragma unroll
        for (int kk = 0; kk < 2; ++kk) {
            const int lka = ((kk * 4 + (lane >> 4)) ^ lr7) * 8;
            s16x8 a[4], b[4];
#pragma unroll
            for (int i = 0; i < 4; ++i)
                a[i] = *(const s16x8*)(As + (wm + i * 16 + lr) * 64 + lka);
#pragma unroll
            for (int j = 0; j < 4; ++j)
                b[j] = *(const s16x8*)(Bs1 + (wn + j * 16 + lr) * 64 + lka);
#pragma unroll
            for (int i = 0; i < 4; ++i)
#pragma unroll
                for (int j = 0; j < 4; ++j)
                    acc1[i][j] = __builtin_amdgcn_mfma_f32_16x16x32_bf16(
                        a[i], b[j], acc1[i][j], 0, 0, 0);
#pragma unroll
            for (int j = 0; j < 4; ++j)
                b[j] = *(const s16x8*)(Bs2 + (wn + j * 16 + lr) * 64 + lka);
#pragma unroll
            for (int i = 0; i < 4; ++i)
#pragma unroll
                for (int j = 0; j < 4; ++j)
                    acc2[i][j] = __builtin_amdgcn_mfma_f32_16x16x32_bf16(
                        a[i], b[j], acc2[i][j], 0, 0, 0);
        }
        __syncthreads();
    }

    const int rbase = wm + (lane >> 4) * 4;
    const int cbase = wn + lr;
    if (qk) {
#pragma unroll
        for (int i = 0; i < 4; ++i)
#pragma unroll
            for (int rr = 0; rr < 4; ++rr) {
                const long long row = row0 + rbase + i * 16 + rr;
#pragma unroll
                for (int j = 0; j < 4; ++j) {
                    const long long col = col0a + cbase + j * 16;
                    qb[row * 1024 + col] = f2bf((acc1[i][j][rr] + bq[col]) * 0.03125f);
                    kb[row * 1024 + col] = f2bf(acc2[i][j][rr] + bk[col]);
                }
            }
    } else {
#pragma unroll
        for (int i = 0; i < 4; ++i)
#pragma unroll
            for (int rr = 0; rr < 4; ++rr) {
                const long long row = row0 + rbase + i * 16 + rr;
                const float bb = bv[row];
#pragma unroll
                for (int j = 0; j < 4; ++j) {
                    const long long ca  = col0a + cbase + j * 16;
                    const long long cb2 = col0b + cbase + j * 16;
                    vtb[row * 8192 + ca]  = f2bf(acc1[i][j][rr] + bb);
                    vtb[row * 8192 + cb2] = f2bf(acc2[i][j][rr] + bb);
                }
            }
    }
}

// EXP: P = exp(Q@K^T) over two adjacent 128-col K-tiles per block, BK=64.
// grid (16 m, 8 col-pairs, 4 batch). Fused row-sum atomics.
__global__ __launch_bounds__(256, 2) void gemm_exp(
    const uint16_t* __restrict__ Q, const uint16_t* __restrict__ Km,
    uint16_t* __restrict__ P, float* __restrict__ sums)
{
    __shared__ __attribute__((aligned(16))) uint16_t As[128 * 64];
    __shared__ __attribute__((aligned(16))) uint16_t Bs1[128 * 64];
    __shared__ __attribute__((aligned(16))) uint16_t Bs2[128 * 64];

    const int z = blockIdx.z;
    const uint16_t* Ab = Q  + (long long)z * 2048 * 1024;
    const uint16_t* Bb = Km + (long long)z * 2048 * 1024;
    uint16_t* Cb = P + (long long)z * 2048 * 2048;
    float* ax = sums + (long long)z * 2048;

    const int t = threadIdx.x;
    const int wave = t >> 6, lane = t & 63;
    const int wm = (wave >> 1) * 64, wn = (wave & 1) * 64;
    const int lr = lane & 15;
    const int lr7 = lr & 7;
    const long long row0  = (long long)blockIdx.x * 128;
    const long long col0a = (long long)blockIdx.y * 256;
    const long long col0b = col0a + 128;

    const uint16_t* gA[4]; const uint16_t* gB1[4]; const uint16_t* gB2[4];
    uint16_t* lA[4]; uint16_t* lB1[4]; uint16_t* lB2[4];
#pragma unroll
    for (int p = 0; p < 4; ++p) {
        const int cs = p * 256 + wave * 64 + lane;
        const int rr = cs >> 3;
        const int kc = ((cs & 7) ^ (rr & 7)) * 8;
        gA[p]  = Ab + (row0  + rr) * 1024 + kc;
        gB1[p] = Bb + (col0a + rr) * 1024 + kc;
        gB2[p] = Bb + (col0b + rr) * 1024 + kc;
        lA[p]  = As  + (p * 256 + wave * 64) * 8;
        lB1[p] = Bs1 + (p * 256 + wave * 64) * 8;
        lB2[p] = Bs2 + (p * 256 + wave * 64) * 8;
    }

    f32x4 acc1[4][4] = {};
    f32x4 acc2[4][4] = {};

    for (int k0 = 0; k0 < 1024; k0 += 64) {
#pragma unroll
        for (int p = 0; p < 4; ++p) GLOAD16(gA[p] + k0, lA[p]);
#pragma unroll
        for (int p = 0; p < 4; ++p) GLOAD16(gB1[p] + k0, lB1[p]);
#pragma unroll
        for (int p = 0; p < 4; ++p) GLOAD16(gB2[p] + k0, lB2[p]);
        __syncthreads();

#pragma unroll
        for (int kk = 0; kk < 2; ++kk) {
            const int lka = ((kk * 4 + (lane >> 4)) ^ lr7) * 8;
            s16x8 a[4], b[4];
#pragma unroll
            for (int i = 0; i < 4; ++i)
                a[i] = *(const s16x8*)(As + (wm + i * 16 + lr) * 64 + lka);
#pragma unroll
            for (int j = 0; j < 4; ++j)
                b[j] = *(const s16x8*)(Bs1 + (wn + j * 16 + lr) * 64 + lka);
#pragma unroll
            for (int i = 0; i < 4; ++i)
#pragma unroll
                for (int j = 0; j < 4; ++j)
                    acc1[i][j] = __builtin_amdgcn_mfma_f32_16x16x32_bf16(
                        a[i], b[j], acc1[i][j], 0, 0, 0);
#pragma unroll
            for (int j = 0; j < 4; ++j)
                b[j] = *(const s16x8*)(Bs2 + (wn + j * 16 + lr) * 64 + lka);
#pragma unroll
            for (int i = 0; i < 4; ++i)
#pragma unroll
                for (int j = 0; j < 4; ++j)
                    acc2[i][j] = __builtin_amdgcn_mfma_f32_16x16x32_bf16(
                        a[i], b[j], acc2[i][j], 0, 0, 0);
        }
        __syncthreads();
    }

    const int rbase = wm + (lane >> 4) * 4;
    const int cbase = wn + lr;
#pragma unroll
    for (int i = 0; i < 4; ++i)
#pragma unroll
        for (int rr = 0; rr < 4; ++rr) {
            const long long row = row0 + rbase + i * 16 + rr;
            float s = 0.f;
#pragma unroll
            for (int j = 0; j < 4; ++j) {
                const long long ca = col0a + cbase + j * 16;
                const long long cb2 = col0b + cbase + j * 16;
                const float va = __expf(acc1[i][j][rr]);
                const float vb = __expf(acc2[i][j][rr]);
                Cb[row * 2048 + ca]  = f2bf(va);
                Cb[row * 2048 + cb2] = f2bf(vb);
                s += va + vb;
            }
            s += __shfl_xor(s, 1);
            s += __shfl_xor(s, 2);
            s += __shfl_xor(s, 4);
            s += __shfl_xor(s, 8);
            if (lr == 0) atomicAdd(&ax[row], s);
        }
}

// PV: out = (P@V) * rcp(sums[row]). BK=64 single-tile, grid (16,8,4) =
// 512 blocks, 2 blocks/CU (R5 config — best measured).
__global__ __launch_bounds__(256, 2) void gemm_pv(
    const uint16_t* __restrict__ P, const uint16_t* __restrict__ Vt,
    float* __restrict__ Out, const float* __restrict__ sums)
{
    __shared__ __attribute__((aligned(16))) uint16_t As[128 * 64];
    __shared__ __attribute__((aligned(16))) uint16_t Bs[128 * 64];

    const int z = blockIdx.z;
    const uint16_t* Ab = P + (long long)z * 2048 * 2048;
    const uint16_t* Bb = Vt + (long long)z * 2048;   // col offset in 8192 dim
    float* Cb = Out + (long long)z * 2048 * 1024;
    const float* ax = sums + (long long)z * 2048;

    const int t = threadIdx.x;
    const int wave = t >> 6, lane = t & 63;
    const int wm = (wave >> 1) * 64, wn = (wave & 1) * 64;
    const int lr = lane & 15;
    const int lr7 = lr & 7;
    const long long row0 = (long long)blockIdx.x * 128;
    const long long col0 = (long long)blockIdx.y * 128;

    const uint16_t* gA[4]; const uint16_t* gB[4];
    uint16_t* lA[4]; uint16_t* lB[4];
#pragma unroll
    for (int p = 0; p < 4; ++p) {
        const int cs = p * 256 + wave * 64 + lane;
        const int rr = cs >> 3;
        const int kc = ((cs & 7) ^ (rr & 7)) * 8;
        gA[p] = Ab + (row0 + rr) * 2048 + kc;
        gB[p] = Bb + (col0 + rr) * 8192 + kc;
        lA[p] = As + (p * 256 + wave * 64) * 8;
        lB[p] = Bs + (p * 256 + wave * 64) * 8;
    }

    f32x4 acc[4][4] = {};

    for (int k0 = 0; k0 < 2048; k0 += 64) {
#pragma unroll
        for (int p = 0; p < 4; ++p) GLOAD16(gA[p] + k0, lA[p]);
#pragma unroll
        for (int p = 0; p < 4; ++p) GLOAD16(gB[p] + k0, lB[p]);
        __syncthreads();

#pragma unroll
        for (int kk = 0; kk < 2; ++kk) {
            const int lka = ((kk * 4 + (lane >> 4)) ^ lr7) * 8;
            s16x8 a[4], b[4];
#pragma unroll
            for (int i = 0; i < 4; ++i)
                a[i] = *(const s16x8*)(As + (wm + i * 16 + lr) * 64 + lka);
#pragma unroll
            for (int j = 0; j < 4; ++j)
                b[j] = *(const s16x8*)(Bs + (wn + j * 16 + lr) * 64 + lka);
#pragma unroll
            for (int i = 0; i < 4; ++i)
#pragma unroll
                for (int j = 0; j < 4; ++j)
                    acc[i][j] = __builtin_amdgcn_mfma_f32_16x16x32_bf16(
                        a[i], b[j], acc[i][j], 0, 0, 0);
        }
        __syncthreads();
    }

    const int rbase = wm + (lane >> 4) * 4;
    const int cbase = wn + lr;
#pragma unroll
    for (int i = 0; i < 4; ++i)
#pragma unroll
        for (int rr = 0; rr < 4; ++rr) {
            const long long row = row0 + rbase + i * 16 + rr;
            const float linv = __builtin_amdgcn_rcpf(ax[row]);
#pragma unroll
            for (int j = 0; j < 4; ++j) {
                const long long col = col0 + cbase + j * 16;
                Cb[row * 1024 + col] = acc[i][j][rr] * linv;
            }
        }
}

// One dispatch: cast x (blocks 0..8191), Wq/Wk/Wv (8192..11263), zero sums.
__global__ void cast_all(const float* __restrict__ x, const float* __restrict__ Wq,
                         const float* __restrict__ Wk, const float* __restrict__ Wv,
                         uint16_t* __restrict__ xb, uint16_t* __restrict__ wqb,
                         uint16_t* __restrict__ wkb, uint16_t* __restrict__ wvb,
                         float* __restrict__ sums) {
    const int b = blockIdx.x;
    const float* in;
    uint16_t* out;
    int i;
    if (b < 8192)       { in = x;  out = xb;  i = b * 256 + threadIdx.x; }
    else if (b < 9216)  { in = Wq; out = wqb; i = (b - 8192) * 256 + threadIdx.x; }
    else if (b < 10240) { in = Wk; out = wkb; i = (b - 9216) * 256 + threadIdx.x; }
    else if (b < 11264) { in = Wv; out = wvb; i = (b - 10240) * 256 + threadIdx.x; }
    else {
        int j = (b - 11264) * 256 + threadIdx.x;   // 8 blocks x 256 x float4 = 8192
        ((float4*)sums)[j] = make_float4(0.f, 0.f, 0.f, 0.f);
        return;
    }
    float4 v = ((const float4*)in)[i];
    ushort4 o = make_ushort4(f2bf(v.x), f2bf(v.y), f2bf(v.z), f2bf(v.w));
    ((ushort4*)out)[i] = o;
}

extern "C" void kernel_launch(void* const* d_in, const int* in_sizes, int n_in,
                              void* d_out, int out_size, void* d_ws, size_t ws_size,
                              hipStream_t stream) {
    const float* x  = (const float*)d_in[0];
    const float* Wq = (const float*)d_in[1];
    const float* bq = (const float*)d_in[2];
    const float* Wk = (const float*)d_in[3];
    const float* bk = (const float*)d_in[4];
    const float* Wv = (const float*)d_in[5];
    const float* bv = (const float*)d_in[6];

    // workspace carve (~102 MiB)
    uint8_t* w = (uint8_t*)d_ws;
    uint16_t* xb  = (uint16_t*)w; w += (size_t)8192 * 1024 * 2;
    uint16_t* wqb = (uint16_t*)w; w += (size_t)1024 * 1024 * 2;
    uint16_t* wkb = (uint16_t*)w; w += (size_t)1024 * 1024 * 2;
    uint16_t* wvb = (uint16_t*)w; w += (size_t)1024 * 1024 * 2;
    uint16_t* qb  = (uint16_t*)w; w += (size_t)8192 * 1024 * 2;
    uint16_t* kb  = (uint16_t*)w; w += (size_t)8192 * 1024 * 2;
    uint16_t* vtb = (uint16_t*)w; w += (size_t)8192 * 1024 * 2;   // [1024][8192]
    uint16_t* pb  = (uint16_t*)w; w += (size_t)4 * 2048 * 2048 * 2;
    float*    sums = (float*)w;  w += (size_t)8192 * 4;

    // casts + zero the exp-sum accumulator (1 dispatch)
    cast_all<<<dim3(11272), dim3(256), 0, stream>>>(x, Wq, Wk, Wv,
                                                    xb, wqb, wkb, wvb, sums);
    // Q (pre-scaled 2^-5) & K fused; V^T dual col-tiles (768 blocks)
    proj_qkv<<<dim3(768), 256, 0, stream>>>(xb, wqb, wkb, wvb, bq, bk, bv,
                                            qb, kb, vtb);
    // P = exp(Q @ K^T) + fused row sums, two K-col tiles per block
    gemm_exp<<<dim3(16, 8, 4), 256, 0, stream>>>(qb, kb, pb, sums);
    // out = (P @ V) * rcp(sums), single-tile, 2 blocks/CU
    gemm_pv<<<dim3(16, 8, 4), 256, 0, stream>>>(pb, vtb, (float*)d_out, sums);
}